// Round 11
// baseline (1419.025 us; speedup 1.0000x reference)
//
#include <hip/hip_runtime.h>
#include <hip/hip_bf16.h>
#include <math.h>

#define BB 4
#define TT 16
#define IMGSZ 256
#define PPATCH 256   // P = tokens per frame
#define PQ 256       // PP = pixels per patch
#define HH 512
#define FFDIM 2048
#define LLAYERS 4
#define NHEADS 8
#define HD 64

#define NTOK (BB*TT*PPATCH)   // 16384

typedef unsigned short bfu;
typedef unsigned int u32;
typedef short bf16x8 __attribute__((ext_vector_type(8)));
typedef float f32x4 __attribute__((ext_vector_type(4)));

__device__ inline float bf2f(bfu u) {
    union { unsigned int i; float f; } cv; cv.i = ((unsigned int)u) << 16; return cv.f;
}
__device__ inline bfu f2bf(float f) {
    __hip_bfloat16 h = __float2bfloat16(f);
    union { __hip_bfloat16 h; bfu u; } cv; cv.h = h; return cv.u;
}
__device__ inline float u_lo(unsigned int u) {
    union { unsigned int i; float f; } cv; cv.i = u << 16; return cv.f;
}
__device__ inline float u_hi(unsigned int u) {
    union { unsigned int i; float f; } cv; cv.i = u & 0xffff0000u; return cv.f;
}
__device__ inline unsigned int pack2(float a, float b) {
    return (unsigned int)f2bf(a) | ((unsigned int)f2bf(b) << 16);
}
__device__ inline unsigned int addbf2(unsigned int a, unsigned int b) {
    return pack2(u_lo(a) + u_lo(b), u_hi(a) + u_hi(b));
}
// async global->LDS, 16B per lane; lds dest = wave-uniform base + lane*16
__device__ __forceinline__ void gload16(const void* g, void* l) {
    __builtin_amdgcn_global_load_lds(
        (const __attribute__((address_space(1))) u32*)g,
        (__attribute__((address_space(3))) u32*)l, 16, 0, 0);
}

// per-layer converted-weight layout (element offsets, all bf16)
#define WL_SQKV 0
#define WL_SO   786432
#define WL_TQKV 1048576
#define WL_TO   1835008
#define WL_FF1  2097152
#define WL_FF2  3145728
#define WL_TOT  4194304
// persistent: skips (6x512x512), head (256x512), patch (512x256)
#define WP_SKIP 0
#define WP_HEAD 1572864
#define WP_PATCH 1703936
#define WP_TOT  1835008

// ---------------------------------------------------------------- patchify (fp32 in -> bf16 out)
__global__ __launch_bounds__(256) void patchify_k(const float* __restrict__ x,
                                                  bfu* __restrict__ xp) {
    int idx = blockIdx.x * 256 + threadIdx.x;      // NTOK*PQ
    int col = idx & 255;
    int row = idx >> 8;
    int p   = row & 255;
    int bt  = row >> 8;
    int gr = p >> 4, gc = p & 15;
    int pr = col >> 4, pc = col & 15;
    xp[idx] = f2bf(x[(size_t)bt * 65536 + (gr * 16 + pr) * 256 + gc * 16 + pc]);
}

// ---------------------------------------------------------------- pos add (bf16 inout)
__global__ __launch_bounds__(256) void addpos_k(bfu* __restrict__ tok,
                                                const float* __restrict__ tpos,
                                                const float* __restrict__ spos) {
    int idx = blockIdx.x * 256 + threadIdx.x;      // NTOK*HH
    int h = idx & 511;
    int p = (idx >> 9) & 255;
    int t = (idx >> 17) & 15;
    tok[idx] = f2bf(bf2f(tok[idx]) + tpos[t * HH + h] + spos[p * HH + h]);
}

// ---------------------------------------------------------------- persistent weight convert
__global__ __launch_bounds__(256) void convpers_k(const float* __restrict__ skw,
                                                  const float* __restrict__ skm,
                                                  const float* __restrict__ hw,
                                                  const float* __restrict__ hm,
                                                  const float* __restrict__ pw,
                                                  bfu* __restrict__ out) {
    int g8 = blockIdx.x * 256 + threadIdx.x;   // 229376 groups of 8
    int idx = g8 * 8;
    const float* src; const float* msk = nullptr; int off;
    if (idx < WP_HEAD)       { src = skw; msk = skm; off = idx; }
    else if (idx < WP_PATCH) { src = hw;  msk = hm;  off = idx - WP_HEAD; }
    else                     { src = pw;             off = idx - WP_PATCH; }
    float4 a = *(const float4*)(src + off);
    float4 b = *(const float4*)(src + off + 4);
    if (msk) {
        float4 ma = *(const float4*)(msk + off), mb = *(const float4*)(msk + off + 4);
        a.x *= ma.x; a.y *= ma.y; a.z *= ma.z; a.w *= ma.w;
        b.x *= mb.x; b.y *= mb.y; b.z *= mb.z; b.w *= mb.w;
    }
    uint4 o = { pack2(a.x, a.y), pack2(a.z, a.w), pack2(b.x, b.y), pack2(b.z, b.w) };
    *(uint4*)(out + idx) = o;
}

// ---------------------------------------------------------------- per-layer weight convert
__global__ __launch_bounds__(256) void convw_k(const float* __restrict__ sq, const float* __restrict__ sk,
                                               const float* __restrict__ sv, const float* __restrict__ so,
                                               const float* __restrict__ tq, const float* __restrict__ tk,
                                               const float* __restrict__ tv, const float* __restrict__ to,
                                               const float* __restrict__ ff1, const float* __restrict__ ff2,
                                               const float* __restrict__ wom, const float* __restrict__ ffm,
                                               const float* __restrict__ sqb, const float* __restrict__ skb,
                                               const float* __restrict__ svb, const float* __restrict__ tqb,
                                               const float* __restrict__ tkb, const float* __restrict__ tvb,
                                               bfu* __restrict__ out,
                                               float* __restrict__ bias_s, float* __restrict__ bias_t) {
    int g8 = blockIdx.x * 256 + threadIdx.x;   // 524288 groups of 8
    if (g8 < 384) {   // fused QKV biases (2 x 1536 fp32)
        int bi = g8 * 8;
        const float* bsrc; float* bdst;
        if (bi < 1536) {
            int o = bi; bdst = bias_s + o;
            bsrc = (o < 512 ? sqb : o < 1024 ? skb : svb) + (o & 511);
        } else {
            int o = bi - 1536; bdst = bias_t + o;
            bsrc = (o < 512 ? tqb : o < 1024 ? tkb : tvb) + (o & 511);
        }
        *(float4*)bdst = *(const float4*)bsrc;
        *(float4*)(bdst + 4) = *(const float4*)(bsrc + 4);
    }
    int idx = g8 * 8;
    const float* src; const float* msk = nullptr; int off;
    if (idx < WL_SO) {
        int r = idx; src = (r < 262144 ? sq : r < 524288 ? sk : sv); off = r & 262143;
    } else if (idx < WL_TQKV) { src = so; msk = wom; off = idx - WL_SO; }
    else if (idx < WL_TO) {
        int r = idx - WL_TQKV; src = (r < 262144 ? tq : r < 524288 ? tk : tv); off = r & 262143;
    } else if (idx < WL_FF1) { src = to; msk = wom; off = idx - WL_TO; }
    else if (idx < WL_FF2)   { src = ff1; msk = ffm; off = idx - WL_FF1; }
    else                     { src = ff2; off = idx - WL_FF2; }
    float4 a = *(const float4*)(src + off);
    float4 b = *(const float4*)(src + off + 4);
    if (msk) {
        float4 ma = *(const float4*)(msk + off), mb = *(const float4*)(msk + off + 4);
        a.x *= ma.x; a.y *= ma.y; a.z *= ma.z; a.w *= ma.w;
        b.x *= mb.x; b.y *= mb.y; b.z *= mb.z; b.w *= mb.w;
    }
    uint4 o = { pack2(a.x, a.y), pack2(a.z, a.w), pack2(b.x, b.y), pack2(b.z, b.w) };
    *(uint4*)(out + idx) = o;
}

// ---------------------------------------------------------------- layernorm (bf16 in/out, fp32 math)
__global__ __launch_bounds__(256) void ln_k(const bfu* __restrict__ X,
                                            const float* __restrict__ g,
                                            const float* __restrict__ b,
                                            bfu* __restrict__ Y,
                                            int rows, int mode) {
    int wave = threadIdx.x >> 6;
    int lane = threadIdx.x & 63;
    int row = blockIdx.x * 4 + wave;
    if (row >= rows) return;
    int inRow = row, outRow = row;
    if (mode == 2) {
        int bb = row >> 8; int p = row & 255;
        inRow = ((bb * TT + (TT - 1)) << 8) + p;
    } else if (mode == 1) {
        int bb = row >> 12;
        int r  = row & 4095;
        int t  = r >> 8;
        int p  = r & 255;
        outRow = (((bb << 8) + p) << 4) + t;    // (b*P+p)*T + t
    }
    const bfu* xr = X + (size_t)inRow * HH;
    bfu vv[8];
    *(uint4*)vv = *(const uint4*)(xr + lane * 8);
    float v[8];
    float s = 0.f;
    #pragma unroll
    for (int i = 0; i < 8; i++) { v[i] = bf2f(vv[i]); s += v[i]; }
    #pragma unroll
    for (int off = 32; off; off >>= 1) s += __shfl_xor(s, off, 64);
    float mean = s * (1.f / 512.f);
    float vs = 0.f;
    #pragma unroll
    for (int i = 0; i < 8; i++) { float d = v[i] - mean; vs += d * d; }
    #pragma unroll
    for (int off = 32; off; off >>= 1) vs += __shfl_xor(vs, off, 64);
    float rstd = rsqrtf(vs * (1.f / 512.f) + 1e-5f);
    bfu out[8];
    #pragma unroll
    for (int i = 0; i < 8; i++) {
        int c = lane * 8 + i;
        out[i] = f2bf((v[i] - mean) * rstd * g[c] + b[c]);
    }
    *(uint4*)(Y + (size_t)outRow * HH + lane * 8) = *(uint4*)out;
}

// ================================================================ shared GEMM machinery
#define XCD_SWZ(wid)                                                           \
    const int nwg = gridDim.x;                                                 \
    const int id = blockIdx.x;                                                 \
    const int q = nwg >> 3, r = nwg & 7;                                       \
    const int xcd = id & 7, sub = id >> 3;                                     \
    const int wid = (xcd < r ? xcd * (q + 1) : r * (q + 1) + (xcd - r) * q) + sub;

#define VWAIT4 do { asm volatile("s_waitcnt vmcnt(4)" ::: "memory");           \
                    __builtin_amdgcn_sched_barrier(0); } while (0)
#define VWAIT6 do { asm volatile("s_waitcnt vmcnt(6)" ::: "memory");           \
                    __builtin_amdgcn_sched_barrier(0); } while (0)
#define VWAIT0 do { asm volatile("s_waitcnt vmcnt(0)" ::: "memory");           \
                    __builtin_amdgcn_sched_barrier(0); } while (0)
#define BAR    do { __builtin_amdgcn_s_barrier();                              \
                    __builtin_amdgcn_sched_barrier(0); } while (0)

// ---------------------------------------------------------------- MFMA GEMM, multi-segment K
// C[M,N] = act( sum_s A_s[M,Ks] * W_s[N,Ks]^T + bias[N] ) + addTo[M,N]
// tile 128x128, BK=32; 3-buffer depth-2 pipeline; T2 swizzle; XCD-chunk swizzle;
// T5 setprio; LDS-bounce coalesced epilogue.
__device__ __forceinline__ void seg_ptrs(int s,
    const bfu* A0, const bfu* W0, int K0, const bfu* A1, const bfu* W1, int K1,
    const bfu* A2, const bfu* W2, int K2, const bfu* A3, const bfu* W3, int K3,
    const bfu*& pa, const bfu*& pw, int& kk) {
    switch (s) {
        case 0:  pa = A0; pw = W0; kk = K0; break;
        case 1:  pa = A1; pw = W1; kk = K1; break;
        case 2:  pa = A2; pw = W2; kk = K2; break;
        default: pa = A3; pw = W3; kk = K3; break;
    }
}

#define CTS 136   // C-bounce LDS row stride (272B: 16B-aligned, 2-way banks max)

template<int ACT>
__global__ __launch_bounds__(256) void gemm3_k(
    const bfu* __restrict__ A0, const bfu* __restrict__ W0, int K0,
    const bfu* __restrict__ A1, const bfu* __restrict__ W1, int K1,
    const bfu* __restrict__ A2, const bfu* __restrict__ W2, int K2,
    const bfu* __restrict__ A3, const bfu* __restrict__ W3, int K3,
    int nseg,
    const float* __restrict__ bias, const bfu* __restrict__ addTo,
    bfu* __restrict__ C, int M, int N, int nx) {
    __shared__ __align__(16) bfu S[3][2][128 * 32];   // 48 KB; reused as C-bounce (128*CTS=34 KB)
    XCD_SWZ(wid);
    const int bm = (wid / nx) * 128, bn = (wid % nx) * 128;

    const int tid = threadIdx.x, wave = tid >> 6, lane = tid & 63;
    const int wr = (wave >> 1) * 64, wc = (wave & 1) * 64;
    const int srow = wave * 32 + (lane >> 2);
    const int skoff = (((lane & 3) ^ ((lane >> 3) & 3)) * 8);
    const int frow = lane & 15;
    const int fk = (((lane >> 4) ^ ((frow >> 1) & 3)) * 8);

    const bfu *pa, *pw; int kseg;
    int seg = 0;
    seg_ptrs(0, A0, W0, K0, A1, W1, K1, A2, W2, K2, A3, W3, K3, pa, pw, kseg);
    const bfu* as0 = pa + (size_t)(bm + srow) * kseg + skoff;
    const bfu* as1 = as0 + (size_t)16 * kseg;
    const bfu* ws0 = pw + (size_t)(bn + srow) * kseg + skoff;
    const bfu* ws1 = ws0 + (size_t)16 * kseg;
    int kleft = kseg;
    const int tot = (K0 + K1 + K2 + K3) >> 5;

    f32x4 acc[4][4];
    const f32x4 zero = {0.f, 0.f, 0.f, 0.f};
    #pragma unroll
    for (int m = 0; m < 4; m++)
        #pragma unroll
        for (int n = 0; n < 4; n++) acc[m][n] = zero;

    #define STAGE(buf)                                                         \
        do {                                                                   \
            gload16(as0, &S[buf][0][(wave * 32) * 32]);                        \
            gload16(as1, &S[buf][0][(wave * 32 + 16) * 32]);                   \
            gload16(ws0, &S[buf][1][(wave * 32) * 32]);                        \
            gload16(ws1, &S[buf][1][(wave * 32 + 16) * 32]);                   \
            as0 += 32; as1 += 32; ws0 += 32; ws1 += 32;                        \
            kleft -= 32;                                                       \
            if (kleft == 0 && seg + 1 < nseg) {                                \
                seg++;                                                         \
                seg_ptrs(seg, A0, W0, K0, A1, W1, K1, A2, W2, K2, A3, W3, K3,  \
                         pa, pw, kseg);                                        \
                as0 = pa + (size_t)(bm + srow) * kseg + skoff;                 \
                as1 = as0 + (size_t)16 * kseg;                                 \
                ws0 = pw + (size_t)(bn + srow) * kseg + skoff;                 \
                ws1 = ws0 + (size_t)16 * kseg;                                 \
                kleft = kseg;                                                  \
            }                                                                  \
        } while (0)

    #define COMPUTE(buf)                                                       \
        do {                                                                   \
            bf16x8 af[4], bfr[4];                                              \
            _Pragma("unroll")                                                  \
            for (int m = 0; m < 4; m++)                                        \
                af[m] = *(const bf16x8*)&S[buf][0][(wr + m * 16 + frow) * 32 + fk]; \
            _Pragma("unroll")                                                  \
            for (int n = 0; n < 4; n++)                                        \
                bfr[n] = *(const bf16x8*)&S[buf][1][(wc + n * 16 + frow) * 32 + fk]; \
            __builtin_amdgcn_s_setprio(1);                                     \
            _Pragma("unroll")                                                  \
            for (int m = 0; m < 4; m++)                                        \
                _Pragma("unroll")                                              \
                for (int n = 0; n < 4; n++)                                    \
                    acc[m][n] = __builtin_amdgcn_mfma_f32_16x16x32_bf16(       \
                        af[m], bfr[n], acc[m][n], 0, 0, 0);                    \
            __builtin_amdgcn_s_setprio(0);                                     \
        } while (0)

    STAGE(0);
    STAGE(1);
    VWAIT4;
    BAR;
    int cur = 0, sb = 2;
    for (int t = 0; t < tot; t++) {
        const bool pf = (t + 2 < tot);
        if (pf) { STAGE(sb); sb = (sb == 2) ? 0 : sb + 1; }
        COMPUTE(cur);
        cur = (cur == 2) ? 0 : cur + 1;
        if (t + 1 < tot) {
            if (pf) { VWAIT4; } else { VWAIT0; }
            BAR;
        }
    }
    #undef STAGE
    #undef COMPUTE

    // ---- epilogue: acc -> LDS bounce -> coalesced 16B global stores
    bfu* Ct = &S[0][0][0];
    __syncthreads();          // all waves done reading staging LDS
    const int erow = (lane >> 4) * 4, ecol = lane & 15;
    float bv[4];
    #pragma unroll
    for (int n = 0; n < 4; n++) bv[n] = bias ? bias[bn + wc + n * 16 + ecol] : 0.f;
    #pragma unroll
    for (int m = 0; m < 4; m++) {
        #pragma unroll
        for (int n = 0; n < 4; n++) {
            #pragma unroll
            for (int r2 = 0; r2 < 4; r2++) {
                float v = acc[m][n][r2] + bv[n];
                if (ACT == 1) v = v > 0.f ? v : 0.f;
                if (ACT == 2) v = 1.f / (1.f + __expf(-v));
                Ct[(wr + m * 16 + erow + r2) * CTS + wc + n * 16 + ecol] = f2bf(v);
            }
        }
    }
    __syncthreads();
    #pragma unroll
    for (int it = 0; it < 8; it++) {
        int row = it * 16 + (tid >> 4);
        int col = (tid & 15) * 8;
        uint4 v = *(const uint4*)&Ct[row * CTS + col];
        size_t goff = (size_t)(bm + row) * N + bn + col;
        if (addTo) {
            uint4 t4 = *(const uint4*)(addTo + goff);
            v.x = addbf2(v.x, t4.x); v.y = addbf2(v.y, t4.y);
            v.z = addbf2(v.z, t4.z); v.w = addbf2(v.w, t4.w);
        }
        *(uint4*)(C + goff) = v;
    }
}

// ---------------------------------------------------------------- big-tile MFMA GEMM
// C[M,N] = act( A[M,K] * W[N,K]^T + bias[N] ); tile 256x128, 4 waves (2Mx2N),
// wave tile 128x64 (12 ds_read per 32 MFMA = 384 B/MFMA). Same 3-buffer depth-2
// counted-vmcnt schedule as gemm3_k; vmcnt count from the T4 formula: 6 loads/STAGE.
template<int ACT>
__global__ __launch_bounds__(256) void gemm5_k(
    const bfu* __restrict__ A, const bfu* __restrict__ W,
    const float* __restrict__ bias, bfu* __restrict__ C,
    int M, int N, int K, int nx) {
    __shared__ __align__(16) bfu S[3][384 * 32];   // per buf: A 256 rows | B 128 rows (72 KB)
    XCD_SWZ(wid);
    const int bm = (wid / nx) * 256, bn = (wid % nx) * 128;

    const int tid = threadIdx.x, wave = tid >> 6, lane = tid & 63;
    const int wr = (wave >> 1) * 128, wc = (wave & 1) * 64;
    const int r16 = lane >> 2;
    const int skoff = (((lane & 3) ^ ((lane >> 3) & 3)) * 8);
    const int frow = lane & 15;
    const int fk = (((lane >> 4) ^ ((frow >> 1) & 3)) * 8);

    const bfu* aSrc = A + (size_t)(bm + wave * 64 + r16) * K + skoff;
    const bfu* wSrc = W + (size_t)(bn + wave * 32 + r16) * K + skoff;
    const size_t k16 = (size_t)16 * K;
    const int tot = K >> 5;

    f32x4 acc[8][4];
    const f32x4 zero = {0.f, 0.f, 0.f, 0.f};
    #pragma unroll
    for (int m = 0; m < 8; m++)
        #pragma unroll
        for (int n = 0; n < 4; n++) acc[m][n] = zero;

    #define STAGE5(buf)                                                        \
        do {                                                                   \
            bfu* sa  = &S[buf][(wave * 64) * 32];                              \
            bfu* sbw = &S[buf][256 * 32 + (wave * 32) * 32];                   \
            gload16(aSrc,            sa);                                      \
            gload16(aSrc + k16,      sa + 16 * 32);                            \
            gload16(aSrc + 2 * k16,  sa + 32 * 32);                            \
            gload16(aSrc + 3 * k16,  sa + 48 * 32);                            \
            gload16(wSrc,            sbw);                                     \
            gload16(wSrc + k16,      sbw + 16 * 32);                           \
            aSrc += 32; wSrc += 32;                                            \
        } while (0)

    #define COMPUTE5(buf)                                                      \
        do {                                                                   \
            bf16x8 af[8], bfr[4];                                              \
            _Pragma("unroll")                                                  \
            for (int m = 0; m < 8; m++)                                        \
                af[m] = *(const bf16x8*)&S[buf][(wr + m * 16 + frow) * 32 + fk]; \
            _Pragma("unroll")                                                  \
            for (int n = 0; n < 4; n++)                                        \
                bfr[n] = *(const bf16x8*)&S[buf][256 * 32 + (wc + n * 16 + frow) * 32 + fk]; \
            __builtin_amdgcn_s_setprio(1);                                     \
            _Pragma("unroll")                                                  \
            for (int m = 0; m < 8; m++)                                        \
                _Pragma("unroll")                                              \
                for (int n = 0; n < 4; n++)                                    \
                    acc[m][n] = __builtin_amdgcn_mfma_f32_16x16x32_bf16(       \
                        af[m], bfr[n], acc[m][n], 0, 0, 0);                    \
            __builtin_amdgcn_s_setprio(0);                                     \
        } while (0)

    STAGE5(0);
    STAGE5(1);
    VWAIT6;
    BAR;
    int cur = 0, sb = 2;
    for (int t = 0; t < tot; t++) {
        const bool pf = (t + 2 < tot);
        if (pf) { STAGE5(sb); sb = (sb == 2) ? 0 : sb + 1; }
        COMPUTE5(cur);
        cur = (cur == 2) ? 0 : cur + 1;
        if (t + 1 < tot) {
            if (pf) { VWAIT6; } else { VWAIT0; }
            BAR;
        }
    }
    #undef STAGE5
    #undef COMPUTE5

    // ---- epilogue: acc -> LDS bounce (256 x CTS = 68 KB, fits 72 KB) -> coalesced stores
    bfu* Ct = &S[0][0];
    __syncthreads();
    const int erow = (lane >> 4) * 4, ecol = lane & 15;
    float bv[4];
    #pragma unroll
    for (int n = 0; n < 4; n++) bv[n] = bias ? bias[bn + wc + n * 16 + ecol] : 0.f;
    #pragma unroll
    for (int m = 0; m < 8; m++) {
        #pragma unroll
        for (int n = 0; n < 4; n++) {
            #pragma unroll
            for (int r2 = 0; r2 < 4; r2++) {
                float v = acc[m][n][r2] + bv[n];
                if (ACT == 1) v = v > 0.f ? v : 0.f;
                Ct[(wr + m * 16 + erow + r2) * CTS + wc + n * 16 + ecol] = f2bf(v);
            }
        }
    }
    __syncthreads();
    #pragma unroll
    for (int it = 0; it < 16; it++) {
        int row = it * 16 + (tid >> 4);
        int col = (tid & 15) * 8;
        uint4 v = *(const uint4*)&Ct[row * CTS + col];
        *(uint4*)(C + (size_t)(bm + row) * N + bn + col) = v;
    }
}

// ---------------------------------------------------------------- spatial attention (MFMA flash)
#define VTS 264   // V^T row stride (u16)
#define PTS 72    // P^T row stride (u16)
__global__ __launch_bounds__(256, 2) void sattn_k(const bfu* __restrict__ QKV,
                                                  const float* __restrict__ mask,
                                                  bfu* __restrict__ O) {
    __shared__ __align__(16) bfu Vt[64][VTS];
    __shared__ __align__(16) bfu Pt[4][64][PTS];
    const int gh = blockIdx.x, g = gh >> 3, head = gh & 7;
    const int tid = threadIdx.x, wave = tid >> 6, lane = tid & 63;
    const size_t rbase = (size_t)g * 256;
    const size_t qoff = (size_t)head * 64, koff = qoff + 512, voff = qoff + 1024;

    {   // transpose V (this head, 256 keys x 64 d) into Vt[d][key]
        const bfu* vp = QKV + (rbase + tid) * 1536 + voff;
        bfu vals[64];
        #pragma unroll
        for (int c = 0; c < 8; c++) *(uint4*)&vals[c * 8] = *(const uint4*)(vp + c * 8);
        #pragma unroll
        for (int d = 0; d < 64; d++) Vt[d][tid] = vals[d];
    }
    __syncthreads();

    const int l15 = lane & 15, l4 = lane >> 4;
    const int wq0 = wave * 64;

    bf16x8 Qb[4][2];
    #pragma unroll
    for (int n = 0; n < 4; n++)
        #pragma unroll
        for (int kr = 0; kr < 2; kr++)
            Qb[n][kr] = *(const bf16x8*)(QKV + (rbase + wq0 + n * 16 + l15) * 1536 + qoff + kr * 32 + l4 * 8);

    f32x4 acc_o[4][4];
    const f32x4 zero = {0.f, 0.f, 0.f, 0.f};
    #pragma unroll
    for (int m = 0; m < 4; m++)
        #pragma unroll
        for (int n = 0; n < 4; n++) acc_o[m][n] = zero;
    float m_run[4] = {-3e38f, -3e38f, -3e38f, -3e38f};
    float l_run[4] = {0.f, 0.f, 0.f, 0.f};

    for (int kt = 0; kt < 4; kt++) {
        f32x4 acc_s[4][4];
        #pragma unroll
        for (int m = 0; m < 4; m++)
            #pragma unroll
            for (int n = 0; n < 4; n++) acc_s[m][n] = zero;
        #pragma unroll
        for (int m = 0; m < 4; m++) {
            const bfu* kp = QKV + (rbase + kt * 64 + m * 16 + l15) * 1536 + koff + l4 * 8;
            bf16x8 Ka0 = *(const bf16x8*)kp;
            bf16x8 Ka1 = *(const bf16x8*)(kp + 32);
            #pragma unroll
            for (int n = 0; n < 4; n++) {
                acc_s[m][n] = __builtin_amdgcn_mfma_f32_16x16x32_bf16(Ka0, Qb[n][0], acc_s[m][n], 0, 0, 0);
                acc_s[m][n] = __builtin_amdgcn_mfma_f32_16x16x32_bf16(Ka1, Qb[n][1], acc_s[m][n], 0, 0, 0);
            }
        }
        #pragma unroll
        for (int m = 0; m < 4; m++)
            #pragma unroll
            for (int n = 0; n < 4; n++) {
                float4 mv = *(const float4*)(mask + (size_t)(wq0 + n * 16 + l15) * 256 + kt * 64 + m * 16 + l4 * 4);
                acc_s[m][n][0] = acc_s[m][n][0] * 0.125f + (mv.x - 0.5f) * 20.f;
                acc_s[m][n][1] = acc_s[m][n][1] * 0.125f + (mv.y - 0.5f) * 20.f;
                acc_s[m][n][2] = acc_s[m][n][2] * 0.125f + (mv.z - 0.5f) * 20.f;
                acc_s[m][n][3] = acc_s[m][n][3] * 0.125f + (mv.w - 0.5f) * 20.f;
            }
        #pragma unroll
        for (int n = 0; n < 4; n++) {
            float tmax = acc_s[0][n][0];
            #pragma unroll
            for (int m = 0; m < 4; m++)
                #pragma unroll
                for (int r = 0; r < 4; r++) tmax = fmaxf(tmax, acc_s[m][n][r]);
            tmax = fmaxf(tmax, __shfl_xor(tmax, 16, 64));
            tmax = fmaxf(tmax, __shfl_xor(tmax, 32, 64));
            float newm = fmaxf(m_run[n], tmax);
            float corr = __expf(m_run[n] - newm);
            m_run[n] = newm;
            float esum = 0.f;
            #pragma unroll
            for (int m = 0; m < 4; m++) {
                #pragma unroll
                for (int r = 0; r < 4; r++) {
                    float p = __expf(acc_s[m][n][r] - newm);
                    acc_s[m][n][r] = p;
                    esum += p;
                }
            }
            esum += __shfl_xor(esum, 16, 64);
            esum += __shfl_xor(esum, 32, 64);
            l_run[n] = l_run[n] * corr + esum;
            #pragma unroll
            for (int m = 0; m < 4; m++) {
                acc_o[m][n][0] *= corr; acc_o[m][n][1] *= corr;
                acc_o[m][n][2] *= corr; acc_o[m][n][3] *= corr;
            }
            #pragma unroll
            for (int m = 0; m < 4; m++) {
                uint2 pw = { pack2(acc_s[m][n][0], acc_s[m][n][1]),
                             pack2(acc_s[m][n][2], acc_s[m][n][3]) };
                *(uint2*)&Pt[wave][n * 16 + l15][m * 16 + l4 * 4] = pw;
            }
        }
        #pragma unroll
        for (int kr = 0; kr < 2; kr++) {
            bf16x8 Va[4], Pb[4];
            #pragma unroll
            for (int m = 0; m < 4; m++)
                Va[m] = *(const bf16x8*)&Vt[m * 16 + l15][kt * 64 + kr * 32 + l4 * 8];
            #pragma unroll
            for (int n = 0; n < 4; n++)
                Pb[n] = *(const bf16x8*)&Pt[wave][n * 16 + l15][kr * 32 + l4 * 8];
            #pragma unroll
            for (int m = 0; m < 4; m++)
                #pragma unroll
                for (int n = 0; n < 4; n++)
                    acc_o[m][n] = __builtin_amdgcn_mfma_f32_16x16x32_bf16(Va[m], Pb[n], acc_o[m][n], 0, 0, 0);
        }
    }

    float inv[4];
    #pragma unroll
    for (int n = 0; n < 4; n++) inv[n] = 1.f / l_run[n];
    #pragma unroll
    for (int m = 0; m < 4; m++)
        #pragma unroll
        for (int n = 0; n < 4; n++) {
            ushort4 ov = { f2bf(acc_o[m][n][0] * inv[n]), f2bf(acc_o[m][n][1] * inv[n]),
                           f2bf(acc_o[m][n][2] * inv[n]), f2bf(acc_o[m][n][3] * inv[n]) };
            *(ushort4*)(O + (rbase + wq0 + n * 16 + l15) * 512 + head * 64 + m * 16 + l4 * 4) = ov;
        }
}

// ---------------------------------------------------------------- temporal attention
__global__ __launch_bounds__(256) void tattn_k(const bfu* __restrict__ QKV,
                                               const float* __restrict__ mask,
                                               bfu* __restrict__ O) {
    __shared__ __align__(16) bfu Ks[16][520];
    __shared__ __align__(16) bfu Vs[16][520];
    __shared__ __align__(16) bfu Qs[16][520];
    const int bp = blockIdx.x, b = bp >> 8, p = bp & 255;
    const int tid = threadIdx.x, wave = tid >> 6, lane = tid & 63;
    const size_t rb = (size_t)bp * 16;
    {
        int r = tid >> 4, off = (tid & 15) * 32;
        const bfu* qp = QKV + (rb + r) * 1536 + off;
        const bfu* kp = qp + 512;
        const bfu* vp = qp + 1024;
        #pragma unroll
        for (int c = 0; c < 32; c += 8) {
            *(uint4*)&Qs[r][off + c] = *(const uint4*)(qp + c);
            *(uint4*)&Ks[r][off + c] = *(const uint4*)(kp + c);
            *(uint4*)&Vs[r][off + c] = *(const uint4*)(vp + c);
        }
    }
    __syncthreads();
    const int qq = lane >> 4, kk = lane & 15;
    const int dp4 = (lane & 15) * 4;
    const int abase = lane & 48;
    for (int hh = 0; hh < 2; hh++) {
        const int head = wave * 2 + hh, hoff = head * 64;
        for (int qp4 = 0; qp4 < 4; qp4++) {
            const int q = qp4 * 4 + qq;
            float dot = 0.f;
            #pragma unroll
            for (int dg = 0; dg < 8; dg++) {
                const unsigned int* kp = (const unsigned int*)&Ks[kk][hoff + dg * 8];
                const unsigned int* qp = (const unsigned int*)&Qs[q][hoff + dg * 8];
                #pragma unroll
                for (int c = 0; c < 4; c++) {
                    unsigned int ku = kp[c], qu = qp[c];
                    dot += u_lo(ku) * u_lo(qu) + u_hi(ku) * u_hi(qu);
                }
            }
            float sc = dot * 0.125f + (mask[q * 16 + kk] - 0.5f) * 20.f;
            float m = sc;
            #pragma unroll
            for (int off = 1; off < 16; off <<= 1) m = fmaxf(m, __shfl_xor(m, off, 64));
            float e = __expf(sc - m);
            float sum = e;
            #pragma unroll
            for (int off = 1; off < 16; off <<= 1) sum += __shfl_xor(sum, off, 64);
            float a = e / sum;
            float o0 = 0.f, o1 = 0.f, o2 = 0.f, o3 = 0.f;
            #pragma unroll
            for (int k = 0; k < 16; k++) {
                float ak = __shfl(a, abase + k, 64);
                const unsigned int* vp = (const unsigned int*)&Vs[k][hoff + dp4];
                unsigned int u0 = vp[0], u1 = vp[1];
                o0 += ak * u_lo(u0); o1 += ak * u_hi(u0);
                o2 += ak * u_lo(u1); o3 += ak * u_hi(u1);
            }
            size_t orow = ((size_t)((b * 16 + q) * 256 + p)) * 512 + hoff + dp4;
            ushort4 ov = { f2bf(o0), f2bf(o1), f2bf(o2), f2bf(o3) };
            *(ushort4*)(O + orow) = ov;
        }
    }
}

// ---------------------------------------------------------------- unpatchify (bf16 -> fp32 out)
__global__ __launch_bounds__(256) void unpatch_k(const bfu* __restrict__ patches,
                                                 float* __restrict__ pred) {
    int idx = blockIdx.x * 256 + threadIdx.x;   // B*IMG*IMG
    int c = idx & 255;
    int r = (idx >> 8) & 255;
    int bb = idx >> 16;
    int gr = r >> 4, pr = r & 15, gc = c >> 4, pc = c & 15;
    pred[idx] = bf2f(patches[((size_t)(bb * 256 + gr * 16 + gc) << 8) + pr * 16 + pc]);
}

// ---------------------------------------------------------------- host side
static inline void run_gseg(int act,
                            const bfu* A0, const bfu* W0, int K0,
                            const bfu* A1, const bfu* W1, int K1,
                            const bfu* A2, const bfu* W2, int K2,
                            const bfu* A3, const bfu* W3, int K3, int nseg,
                            const float* bias, const bfu* addTo, bfu* C,
                            int M, int N, hipStream_t s) {
    int nx = N / 128;
    int nwg = nx * (M / 128);
    if (act == 0)
        gemm3_k<0><<<nwg, 256, 0, s>>>(A0, W0, K0, A1, W1, K1, A2, W2, K2, A3, W3, K3,
                                       nseg, bias, addTo, C, M, N, nx);
    else if (act == 1)
        gemm3_k<1><<<nwg, 256, 0, s>>>(A0, W0, K0, A1, W1, K1, A2, W2, K2, A3, W3, K3,
                                       nseg, bias, addTo, C, M, N, nx);
    else
        gemm3_k<2><<<nwg, 256, 0, s>>>(A0, W0, K0, A1, W1, K1, A2, W2, K2, A3, W3, K3,
                                       nseg, bias, addTo, C, M, N, nx);
}

static inline void run_g(int act, const bfu* A, const bfu* W, int K,
                         const float* bias, const bfu* addTo, bfu* C,
                         int M, int N, hipStream_t s) {
    run_gseg(act, A, W, K, nullptr, nullptr, 0, nullptr, nullptr, 0,
             nullptr, nullptr, 0, 1, bias, addTo, C, M, N, s);
}

// big-tile path: requires M%256==0 && N%128==0, single segment, no addTo
static inline void run_g5(int act, const bfu* A, const bfu* W, int K,
                          const float* bias, bfu* C, int M, int N, hipStream_t s) {
    int nx = N / 128;
    int nwg = nx * (M / 256);
    if (act == 0)      gemm5_k<0><<<nwg, 256, 0, s>>>(A, W, bias, C, M, N, K, nx);
    else if (act == 1) gemm5_k<1><<<nwg, 256, 0, s>>>(A, W, bias, C, M, N, K, nx);
}

extern "C" void kernel_launch(void* const* d_in, const int* in_sizes, int n_in,
                              void* d_out, int out_size, void* d_ws, size_t ws_size,
                              hipStream_t stream) {
    const float* x        = (const float*)d_in[0];
    const float* s_mask   = (const float*)d_in[1];
    const float* t_mask   = (const float*)d_in[2];
    const float* wo_masks = (const float*)d_in[3];
    const float* ff_masks = (const float*)d_in[4];
    const float* skip_masks = (const float*)d_in[5];
    const float* head_mask  = (const float*)d_in[6];
    const float* patch_w  = (const float*)d_in[7];
    const float* patch_b  = (const float*)d_in[8];
    const float* tpos     = (const float*)d_in[9];
    const float* spos     = (const float*)d_in[10];
    const float* sq_w = (const float*)d_in[11];
    const float* sq_b = (const float*)d_in[12];
    const float* sk_w = (const float*)d_in[13];
    const float* sk_b = (const float*)d_in[14];
    const float* sv_w = (const float*)d_in[15];
    const float* sv_b = (const float*)d_in[16];
    const float* tq_w = (const float*)d_in[17];
    const float* tq_b = (const float*)d_in[18];
    const float* tk_w = (const float*)d_in[19];
    const float* tk_b = (const float*)d_in[20];
    const float* tv_w = (const float*)d_in[21];
    const float* tv_b = (const float*)d_in[22];
    const float* so_w = (const float*)d_in[23];
    const float* to_w = (const float*)d_in[24];
    const float* ln_s_g = (const float*)d_in[25];
    const float* ln_s_b = (const float*)d_in[26];
    const float* ln_t_g = (const float*)d_in[27];
    const float* ln_t_b = (const float*)d_in[28];
    const float* ln_f_g = (const float*)d_in[29];
    const float* ln_f_b = (const float*)d_in[30];
    const float* ff1_w = (const float*)d_in[31];
    const float* ff1_b = (const float*)d_in[32];
    const float* ff2_w = (const float*)d_in[33];
    const float* ff2_b = (const float*)d_in[34];
    const float* skip_w = (const float*)d_in[35];
    const float* lnf_g = (const float*)d_in[36];
    const float* lnf_b = (const float*)d_in[37];
    const float* head_w = (const float*)d_in[38];
    const float* head_b = (const float*)d_in[39];

    bfu* ws = (bfu*)d_ws;
    const size_t ACTE = (size_t)NTOK * HH;     // 8,388,608 elems (16 MB bf16)
    bfu* acts[5];
    for (int i = 0; i < 5; i++) acts[i] = ws + i * ACTE;
    bfu* xln = ws + 5 * ACTE;
    bfu* qkv = ws + 6 * ACTE;      // NTOK x 1536 fused (spans 3*ACTE)
    bfu* ob  = ws + 9 * ACTE;
    bfu* f1  = qkv;                // NTOK*FFDIM = 4*ACTE, spans qkv..ob
    bfu* xp      = ob;             // patchified pixels (NTOK*PQ), pre-layer phase
    bfu* lastln  = xln;            // final LN rows (1024)
    bfu* patches = qkv;            // head output (1024*256)
    bfu* wlayer = ws + 10 * ACTE;            // per-layer bf16 weights (WL_TOT)
    bfu* wpers  = wlayer + WL_TOT;           // persistent bf16 weights (WP_TOT)
    float* bias_s = (float*)(wpers + WP_TOT);
    float* bias_t = bias_s + 1536;
    // total ws use: (10*ACTE + WL_TOT + WP_TOT)*2 + 3072*4 bytes ~= 171.5 MB

    // ---- persistent weight conversion (skips, head, patch)
    convpers_k<<<WP_TOT / 8 / 256, 256, 0, stream>>>(skip_w, skip_masks, head_w, head_mask,
                                                     patch_w, wpers);

    // ---- patch embed
    patchify_k<<<NTOK * PQ / 256, 256, 0, stream>>>(x, xp);
    run_g(0, xp, wpers + WP_PATCH, PQ, patch_b, nullptr, acts[0], NTOK, HH, stream);
    addpos_k<<<NTOK * HH / 256, 256, 0, stream>>>(acts[0], tpos, spos);

    const size_t WS = 512 * 512;
    const size_t FS = 2048 * 512;
    const int srcs[6] = {0, 0, 1, 0, 1, 2};
    const int tgts[6] = {2, 3, 3, 4, 4, 4};

    for (int i = 0; i < LLAYERS; i++) {
        bfu* h   = acts[i];
        bfu* hn  = acts[i + 1];
        // ---- convert this layer's weights (bf16, masks fused, QKV concatenated)
        convw_k<<<WL_TOT / 8 / 256, 256, 0, stream>>>(
            sq_w + i * WS, sk_w + i * WS, sv_w + i * WS, so_w + i * WS,
            tq_w + i * WS, tk_w + i * WS, tv_w + i * WS, to_w + i * WS,
            ff1_w + i * FS, ff2_w + i * FS,
            wo_masks + i * WS, ff_masks + i * FS,
            sq_b + i * HH, sk_b + i * HH, sv_b + i * HH,
            tq_b + i * HH, tk_b + i * HH, tv_b + i * HH,
            wlayer, bias_s, bias_t);
        // ---- spatial attention
        ln_k<<<NTOK / 4, 256, 0, stream>>>(h, ln_s_g + i * HH, ln_s_b + i * HH, xln, NTOK, 0);
        run_g5(0, xln, wlayer + WL_SQKV, HH, bias_s, qkv, NTOK, 1536, stream);
        sattn_k<<<BB * TT * NHEADS, 256, 0, stream>>>(qkv, s_mask, ob);
        run_g(0, ob, wlayer + WL_SO, HH, nullptr, h, hn, NTOK, HH, stream);
        // ---- temporal attention (rows in (b,p,t) order)
        ln_k<<<NTOK / 4, 256, 0, stream>>>(hn, ln_t_g + i * HH, ln_t_b + i * HH, xln, NTOK, 1);
        run_g5(0, xln, wlayer + WL_TQKV, HH, bias_t, qkv, NTOK, 1536, stream);
        tattn_k<<<BB * PPATCH, 256, 0, stream>>>(qkv, t_mask, ob);   // writes (b,t,p)
        run_g(0, ob, wlayer + WL_TO, HH, nullptr, hn, hn, NTOK, HH, stream);
        // ---- feed forward (+ fused skip connections into layer output)
        ln_k<<<NTOK / 4, 256, 0, stream>>>(hn, ln_f_g + i * HH, ln_f_b + i * HH, xln, NTOK, 0);
        run_g5(1, xln, wlayer + WL_FF1, HH, ff1_b + i * FFDIM, f1, NTOK, FFDIM, stream);
        {
            const bfu* Aseg[4] = { f1, nullptr, nullptr, nullptr };
            const bfu* Wseg[4] = { wlayer + WL_FF2, nullptr, nullptr, nullptr };
            int Kseg[4] = { FFDIM, 0, 0, 0 };
            int ns = 1;
            for (int si = 0; si < 6; si++) {
                if (tgts[si] != i + 1) continue;
                Aseg[ns] = acts[srcs[si]];
                Wseg[ns] = wpers + WP_SKIP + si * WS;
                Kseg[ns] = HH;
                ns++;
            }
            run_gseg(0, Aseg[0], Wseg[0], Kseg[0], Aseg[1], Wseg[1], Kseg[1],
                     Aseg[2], Wseg[2], Kseg[2], Aseg[3], Wseg[3], Kseg[3], ns,
                     ff2_b + i * HH, hn, hn, NTOK, HH, stream);
        }
    }

    // ---- head
    ln_k<<<(BB * PPATCH) / 4, 256, 0, stream>>>(acts[4], lnf_g, lnf_b, lastln, BB * PPATCH, 2);
    run_g(2, lastln, wpers + WP_HEAD, HH, head_b, nullptr, patches, BB * PPATCH, PQ, stream);
    unpatch_k<<<BB * IMGSZ * IMGSZ / 256, 256, 0, stream>>>(patches, (float*)d_out);
}

// Round 12
// 1288.142 us; speedup vs baseline: 1.1016x; 1.1016x over previous
//
#include <hip/hip_runtime.h>
#include <hip/hip_bf16.h>
#include <math.h>

#define BB 4
#define TT 16
#define IMGSZ 256
#define PPATCH 256   // P = tokens per frame
#define PQ 256       // PP = pixels per patch
#define HH 512
#define FFDIM 2048
#define LLAYERS 4
#define NHEADS 8
#define HD 64

#define NTOK (BB*TT*PPATCH)   // 16384

typedef unsigned short bfu;
typedef unsigned int u32;
typedef short bf16x8 __attribute__((ext_vector_type(8)));
typedef float f32x4 __attribute__((ext_vector_type(4)));

__device__ inline float bf2f(bfu u) {
    union { unsigned int i; float f; } cv; cv.i = ((unsigned int)u) << 16; return cv.f;
}
__device__ inline bfu f2bf(float f) {
    __hip_bfloat16 h = __float2bfloat16(f);
    union { __hip_bfloat16 h; bfu u; } cv; cv.h = h; return cv.u;
}
__device__ inline float u_lo(unsigned int u) {
    union { unsigned int i; float f; } cv; cv.i = u << 16; return cv.f;
}
__device__ inline float u_hi(unsigned int u) {
    union { unsigned int i; float f; } cv; cv.i = u & 0xffff0000u; return cv.f;
}
__device__ inline unsigned int pack2(float a, float b) {
    return (unsigned int)f2bf(a) | ((unsigned int)f2bf(b) << 16);
}
__device__ inline unsigned int addbf2(unsigned int a, unsigned int b) {
    return pack2(u_lo(a) + u_lo(b), u_hi(a) + u_hi(b));
}
// async global->LDS, 16B per lane; lds dest = wave-uniform base + lane*16
__device__ __forceinline__ void gload16(const void* g, void* l) {
    __builtin_amdgcn_global_load_lds(
        (const __attribute__((address_space(1))) u32*)g,
        (__attribute__((address_space(3))) u32*)l, 16, 0, 0);
}

// per-layer converted-weight layout (element offsets, all bf16)
#define WL_SQKV 0
#define WL_SO   786432
#define WL_TQKV 1048576
#define WL_TO   1835008
#define WL_FF1  2097152
#define WL_FF2  3145728
#define WL_TOT  4194304
// persistent: skips (6x512x512), head (256x512), patch (512x256)
#define WP_SKIP 0
#define WP_HEAD 1572864
#define WP_PATCH 1703936
#define WP_TOT  1835008

// ---------------------------------------------------------------- patchify (fp32 in -> bf16 out)
__global__ __launch_bounds__(256) void patchify_k(const float* __restrict__ x,
                                                  bfu* __restrict__ xp) {
    int idx = blockIdx.x * 256 + threadIdx.x;      // NTOK*PQ
    int col = idx & 255;
    int row = idx >> 8;
    int p   = row & 255;
    int bt  = row >> 8;
    int gr = p >> 4, gc = p & 15;
    int pr = col >> 4, pc = col & 15;
    xp[idx] = f2bf(x[(size_t)bt * 65536 + (gr * 16 + pr) * 256 + gc * 16 + pc]);
}

// ---------------------------------------------------------------- pos add (bf16 inout)
__global__ __launch_bounds__(256) void addpos_k(bfu* __restrict__ tok,
                                                const float* __restrict__ tpos,
                                                const float* __restrict__ spos) {
    int idx = blockIdx.x * 256 + threadIdx.x;      // NTOK*HH
    int h = idx & 511;
    int p = (idx >> 9) & 255;
    int t = (idx >> 17) & 15;
    tok[idx] = f2bf(bf2f(tok[idx]) + tpos[t * HH + h] + spos[p * HH + h]);
}

// ---------------------------------------------------------------- persistent weight convert
__global__ __launch_bounds__(256) void convpers_k(const float* __restrict__ skw,
                                                  const float* __restrict__ skm,
                                                  const float* __restrict__ hw,
                                                  const float* __restrict__ hm,
                                                  const float* __restrict__ pw,
                                                  bfu* __restrict__ out) {
    int g8 = blockIdx.x * 256 + threadIdx.x;   // 229376 groups of 8
    int idx = g8 * 8;
    const float* src; const float* msk = nullptr; int off;
    if (idx < WP_HEAD)       { src = skw; msk = skm; off = idx; }
    else if (idx < WP_PATCH) { src = hw;  msk = hm;  off = idx - WP_HEAD; }
    else                     { src = pw;             off = idx - WP_PATCH; }
    float4 a = *(const float4*)(src + off);
    float4 b = *(const float4*)(src + off + 4);
    if (msk) {
        float4 ma = *(const float4*)(msk + off), mb = *(const float4*)(msk + off + 4);
        a.x *= ma.x; a.y *= ma.y; a.z *= ma.z; a.w *= ma.w;
        b.x *= mb.x; b.y *= mb.y; b.z *= mb.z; b.w *= mb.w;
    }
    uint4 o = { pack2(a.x, a.y), pack2(a.z, a.w), pack2(b.x, b.y), pack2(b.z, b.w) };
    *(uint4*)(out + idx) = o;
}

// ---------------------------------------------------------------- per-layer weight convert
__global__ __launch_bounds__(256) void convw_k(const float* __restrict__ sq, const float* __restrict__ sk,
                                               const float* __restrict__ sv, const float* __restrict__ so,
                                               const float* __restrict__ tq, const float* __restrict__ tk,
                                               const float* __restrict__ tv, const float* __restrict__ to,
                                               const float* __restrict__ ff1, const float* __restrict__ ff2,
                                               const float* __restrict__ wom, const float* __restrict__ ffm,
                                               const float* __restrict__ sqb, const float* __restrict__ skb,
                                               const float* __restrict__ svb, const float* __restrict__ tqb,
                                               const float* __restrict__ tkb, const float* __restrict__ tvb,
                                               bfu* __restrict__ out,
                                               float* __restrict__ bias_s, float* __restrict__ bias_t) {
    int g8 = blockIdx.x * 256 + threadIdx.x;   // 524288 groups of 8
    if (g8 < 384) {   // fused QKV biases (2 x 1536 fp32)
        int bi = g8 * 8;
        const float* bsrc; float* bdst;
        if (bi < 1536) {
            int o = bi; bdst = bias_s + o;
            bsrc = (o < 512 ? sqb : o < 1024 ? skb : svb) + (o & 511);
        } else {
            int o = bi - 1536; bdst = bias_t + o;
            bsrc = (o < 512 ? tqb : o < 1024 ? tkb : tvb) + (o & 511);
        }
        *(float4*)bdst = *(const float4*)bsrc;
        *(float4*)(bdst + 4) = *(const float4*)(bsrc + 4);
    }
    int idx = g8 * 8;
    const float* src; const float* msk = nullptr; int off;
    if (idx < WL_SO) {
        int r = idx; src = (r < 262144 ? sq : r < 524288 ? sk : sv); off = r & 262143;
    } else if (idx < WL_TQKV) { src = so; msk = wom; off = idx - WL_SO; }
    else if (idx < WL_TO) {
        int r = idx - WL_TQKV; src = (r < 262144 ? tq : r < 524288 ? tk : tv); off = r & 262143;
    } else if (idx < WL_FF1) { src = to; msk = wom; off = idx - WL_TO; }
    else if (idx < WL_FF2)   { src = ff1; msk = ffm; off = idx - WL_FF1; }
    else                     { src = ff2; off = idx - WL_FF2; }
    float4 a = *(const float4*)(src + off);
    float4 b = *(const float4*)(src + off + 4);
    if (msk) {
        float4 ma = *(const float4*)(msk + off), mb = *(const float4*)(msk + off + 4);
        a.x *= ma.x; a.y *= ma.y; a.z *= ma.z; a.w *= ma.w;
        b.x *= mb.x; b.y *= mb.y; b.z *= mb.z; b.w *= mb.w;
    }
    uint4 o = { pack2(a.x, a.y), pack2(a.z, a.w), pack2(b.x, b.y), pack2(b.z, b.w) };
    *(uint4*)(out + idx) = o;
}

// ---------------------------------------------------------------- layernorm (bf16 in/out, fp32 math)
__global__ __launch_bounds__(256) void ln_k(const bfu* __restrict__ X,
                                            const float* __restrict__ g,
                                            const float* __restrict__ b,
                                            bfu* __restrict__ Y,
                                            int rows, int mode) {
    int wave = threadIdx.x >> 6;
    int lane = threadIdx.x & 63;
    int row = blockIdx.x * 4 + wave;
    if (row >= rows) return;
    int inRow = row, outRow = row;
    if (mode == 2) {
        int bb = row >> 8; int p = row & 255;
        inRow = ((bb * TT + (TT - 1)) << 8) + p;
    } else if (mode == 1) {
        int bb = row >> 12;
        int r  = row & 4095;
        int t  = r >> 8;
        int p  = r & 255;
        outRow = (((bb << 8) + p) << 4) + t;    // (b*P+p)*T + t
    }
    const bfu* xr = X + (size_t)inRow * HH;
    bfu vv[8];
    *(uint4*)vv = *(const uint4*)(xr + lane * 8);
    float v[8];
    float s = 0.f;
    #pragma unroll
    for (int i = 0; i < 8; i++) { v[i] = bf2f(vv[i]); s += v[i]; }
    #pragma unroll
    for (int off = 32; off; off >>= 1) s += __shfl_xor(s, off, 64);
    float mean = s * (1.f / 512.f);
    float vs = 0.f;
    #pragma unroll
    for (int i = 0; i < 8; i++) { float d = v[i] - mean; vs += d * d; }
    #pragma unroll
    for (int off = 32; off; off >>= 1) vs += __shfl_xor(vs, off, 64);
    float rstd = rsqrtf(vs * (1.f / 512.f) + 1e-5f);
    bfu out[8];
    #pragma unroll
    for (int i = 0; i < 8; i++) {
        int c = lane * 8 + i;
        out[i] = f2bf((v[i] - mean) * rstd * g[c] + b[c]);
    }
    *(uint4*)(Y + (size_t)outRow * HH + lane * 8) = *(uint4*)out;
}

// ================================================================ shared GEMM machinery
#define XCD_SWZ(wid)                                                           \
    const int nwg = gridDim.x;                                                 \
    const int id = blockIdx.x;                                                 \
    const int q = nwg >> 3, r = nwg & 7;                                       \
    const int xcd = id & 7, sub = id >> 3;                                     \
    const int wid = (xcd < r ? xcd * (q + 1) : r * (q + 1) + (xcd - r) * q) + sub;

#define VWAIT4 do { asm volatile("s_waitcnt vmcnt(4)" ::: "memory");           \
                    __builtin_amdgcn_sched_barrier(0); } while (0)
#define VWAIT0 do { asm volatile("s_waitcnt vmcnt(0)" ::: "memory");           \
                    __builtin_amdgcn_sched_barrier(0); } while (0)
#define BAR    do { __builtin_amdgcn_s_barrier();                              \
                    __builtin_amdgcn_sched_barrier(0); } while (0)

// ---------------------------------------------------------------- MFMA GEMM, multi-segment K
// C[M,N] = act( sum_s A_s[M,Ks] * W_s[N,Ks]^T + bias[N] ) + addTo[M,N]
// tile 128x128, BK=32; 3-buffer depth-2 pipeline; T2 swizzle; XCD-chunk swizzle;
// T5 setprio; LDS-bounce coalesced epilogue.
__device__ __forceinline__ void seg_ptrs(int s,
    const bfu* A0, const bfu* W0, int K0, const bfu* A1, const bfu* W1, int K1,
    const bfu* A2, const bfu* W2, int K2, const bfu* A3, const bfu* W3, int K3,
    const bfu*& pa, const bfu*& pw, int& kk) {
    switch (s) {
        case 0:  pa = A0; pw = W0; kk = K0; break;
        case 1:  pa = A1; pw = W1; kk = K1; break;
        case 2:  pa = A2; pw = W2; kk = K2; break;
        default: pa = A3; pw = W3; kk = K3; break;
    }
}

#define CTS 136   // C-bounce LDS row stride (272B: 16B-aligned, 2-way banks max)

template<int ACT>
__global__ __launch_bounds__(256) void gemm3_k(
    const bfu* __restrict__ A0, const bfu* __restrict__ W0, int K0,
    const bfu* __restrict__ A1, const bfu* __restrict__ W1, int K1,
    const bfu* __restrict__ A2, const bfu* __restrict__ W2, int K2,
    const bfu* __restrict__ A3, const bfu* __restrict__ W3, int K3,
    int nseg,
    const float* __restrict__ bias, const bfu* __restrict__ addTo,
    bfu* __restrict__ C, int M, int N, int nx) {
    __shared__ __align__(16) bfu S[3][2][128 * 32];   // 48 KB; reused as C-bounce (128*CTS=34 KB)
    XCD_SWZ(wid);
    const int bm = (wid / nx) * 128, bn = (wid % nx) * 128;

    const int tid = threadIdx.x, wave = tid >> 6, lane = tid & 63;
    const int wr = (wave >> 1) * 64, wc = (wave & 1) * 64;
    const int srow = wave * 32 + (lane >> 2);
    const int skoff = (((lane & 3) ^ ((lane >> 3) & 3)) * 8);
    const int frow = lane & 15;
    const int fk = (((lane >> 4) ^ ((frow >> 1) & 3)) * 8);

    const bfu *pa, *pw; int kseg;
    int seg = 0;
    seg_ptrs(0, A0, W0, K0, A1, W1, K1, A2, W2, K2, A3, W3, K3, pa, pw, kseg);
    const bfu* as0 = pa + (size_t)(bm + srow) * kseg + skoff;
    const bfu* as1 = as0 + (size_t)16 * kseg;
    const bfu* ws0 = pw + (size_t)(bn + srow) * kseg + skoff;
    const bfu* ws1 = ws0 + (size_t)16 * kseg;
    int kleft = kseg;
    const int tot = (K0 + K1 + K2 + K3) >> 5;

    f32x4 acc[4][4];
    const f32x4 zero = {0.f, 0.f, 0.f, 0.f};
    #pragma unroll
    for (int m = 0; m < 4; m++)
        #pragma unroll
        for (int n = 0; n < 4; n++) acc[m][n] = zero;

    #define STAGE(buf)                                                         \
        do {                                                                   \
            gload16(as0, &S[buf][0][(wave * 32) * 32]);                        \
            gload16(as1, &S[buf][0][(wave * 32 + 16) * 32]);                   \
            gload16(ws0, &S[buf][1][(wave * 32) * 32]);                        \
            gload16(ws1, &S[buf][1][(wave * 32 + 16) * 32]);                   \
            as0 += 32; as1 += 32; ws0 += 32; ws1 += 32;                        \
            kleft -= 32;                                                       \
            if (kleft == 0 && seg + 1 < nseg) {                                \
                seg++;                                                         \
                seg_ptrs(seg, A0, W0, K0, A1, W1, K1, A2, W2, K2, A3, W3, K3,  \
                         pa, pw, kseg);                                        \
                as0 = pa + (size_t)(bm + srow) * kseg + skoff;                 \
                as1 = as0 + (size_t)16 * kseg;                                 \
                ws0 = pw + (size_t)(bn + srow) * kseg + skoff;                 \
                ws1 = ws0 + (size_t)16 * kseg;                                 \
                kleft = kseg;                                                  \
            }                                                                  \
        } while (0)

    #define COMPUTE(buf)                                                       \
        do {                                                                   \
            bf16x8 af[4], bfr[4];                                              \
            _Pragma("unroll")                                                  \
            for (int m = 0; m < 4; m++)                                        \
                af[m] = *(const bf16x8*)&S[buf][0][(wr + m * 16 + frow) * 32 + fk]; \
            _Pragma("unroll")                                                  \
            for (int n = 0; n < 4; n++)                                        \
                bfr[n] = *(const bf16x8*)&S[buf][1][(wc + n * 16 + frow) * 32 + fk]; \
            __builtin_amdgcn_s_setprio(1);                                     \
            _Pragma("unroll")                                                  \
            for (int m = 0; m < 4; m++)                                        \
                _Pragma("unroll")                                              \
                for (int n = 0; n < 4; n++)                                    \
                    acc[m][n] = __builtin_amdgcn_mfma_f32_16x16x32_bf16(       \
                        af[m], bfr[n], acc[m][n], 0, 0, 0);                    \
            __builtin_amdgcn_s_setprio(0);                                     \
        } while (0)

    STAGE(0);
    STAGE(1);
    VWAIT4;
    BAR;
    int cur = 0, sb = 2;
    for (int t = 0; t < tot; t++) {
        const bool pf = (t + 2 < tot);
        if (pf) { STAGE(sb); sb = (sb == 2) ? 0 : sb + 1; }
        COMPUTE(cur);
        cur = (cur == 2) ? 0 : cur + 1;
        if (t + 1 < tot) {
            if (pf) { VWAIT4; } else { VWAIT0; }
            BAR;
        }
    }
    #undef STAGE
    #undef COMPUTE

    // ---- epilogue: acc -> LDS bounce -> coalesced 16B global stores
    bfu* Ct = &S[0][0][0];
    __syncthreads();          // all waves done reading staging LDS
    const int erow = (lane >> 4) * 4, ecol = lane & 15;
    float bv[4];
    #pragma unroll
    for (int n = 0; n < 4; n++) bv[n] = bias ? bias[bn + wc + n * 16 + ecol] : 0.f;
    #pragma unroll
    for (int m = 0; m < 4; m++) {
        #pragma unroll
        for (int n = 0; n < 4; n++) {
            #pragma unroll
            for (int r2 = 0; r2 < 4; r2++) {
                float v = acc[m][n][r2] + bv[n];
                if (ACT == 1) v = v > 0.f ? v : 0.f;
                if (ACT == 2) v = 1.f / (1.f + __expf(-v));
                Ct[(wr + m * 16 + erow + r2) * CTS + wc + n * 16 + ecol] = f2bf(v);
            }
        }
    }
    __syncthreads();
    #pragma unroll
    for (int it = 0; it < 8; it++) {
        int row = it * 16 + (tid >> 4);
        int col = (tid & 15) * 8;
        uint4 v = *(const uint4*)&Ct[row * CTS + col];
        size_t goff = (size_t)(bm + row) * N + bn + col;
        if (addTo) {
            uint4 t4 = *(const uint4*)(addTo + goff);
            v.x = addbf2(v.x, t4.x); v.y = addbf2(v.y, t4.y);
            v.z = addbf2(v.z, t4.z); v.w = addbf2(v.w, t4.w);
        }
        *(uint4*)(C + goff) = v;
    }
}

// ---------------------------------------------------------------- spatial attention (MFMA flash)
#define VTS 264   // V^T row stride (u16)
#define PTS 72    // P^T row stride (u16)
__global__ __launch_bounds__(256, 2) void sattn_k(const bfu* __restrict__ QKV,
                                                  const float* __restrict__ mask,
                                                  bfu* __restrict__ O) {
    __shared__ __align__(16) bfu Vt[64][VTS];
    __shared__ __align__(16) bfu Pt[4][64][PTS];
    const int gh = blockIdx.x, g = gh >> 3, head = gh & 7;
    const int tid = threadIdx.x, wave = tid >> 6, lane = tid & 63;
    const size_t rbase = (size_t)g * 256;
    const size_t qoff = (size_t)head * 64, koff = qoff + 512, voff = qoff + 1024;

    {   // transpose V (this head, 256 keys x 64 d) into Vt[d][key]
        const bfu* vp = QKV + (rbase + tid) * 1536 + voff;
        bfu vals[64];
        #pragma unroll
        for (int c = 0; c < 8; c++) *(uint4*)&vals[c * 8] = *(const uint4*)(vp + c * 8);
        #pragma unroll
        for (int d = 0; d < 64; d++) Vt[d][tid] = vals[d];
    }
    __syncthreads();

    const int l15 = lane & 15, l4 = lane >> 4;
    const int wq0 = wave * 64;

    bf16x8 Qb[4][2];
    #pragma unroll
    for (int n = 0; n < 4; n++)
        #pragma unroll
        for (int kr = 0; kr < 2; kr++)
            Qb[n][kr] = *(const bf16x8*)(QKV + (rbase + wq0 + n * 16 + l15) * 1536 + qoff + kr * 32 + l4 * 8);

    f32x4 acc_o[4][4];
    const f32x4 zero = {0.f, 0.f, 0.f, 0.f};
    #pragma unroll
    for (int m = 0; m < 4; m++)
        #pragma unroll
        for (int n = 0; n < 4; n++) acc_o[m][n] = zero;
    float m_run[4] = {-3e38f, -3e38f, -3e38f, -3e38f};
    float l_run[4] = {0.f, 0.f, 0.f, 0.f};

    for (int kt = 0; kt < 4; kt++) {
        f32x4 acc_s[4][4];
        #pragma unroll
        for (int m = 0; m < 4; m++)
            #pragma unroll
            for (int n = 0; n < 4; n++) acc_s[m][n] = zero;
        #pragma unroll
        for (int m = 0; m < 4; m++) {
            const bfu* kp = QKV + (rbase + kt * 64 + m * 16 + l15) * 1536 + koff + l4 * 8;
            bf16x8 Ka0 = *(const bf16x8*)kp;
            bf16x8 Ka1 = *(const bf16x8*)(kp + 32);
            #pragma unroll
            for (int n = 0; n < 4; n++) {
                acc_s[m][n] = __builtin_amdgcn_mfma_f32_16x16x32_bf16(Ka0, Qb[n][0], acc_s[m][n], 0, 0, 0);
                acc_s[m][n] = __builtin_amdgcn_mfma_f32_16x16x32_bf16(Ka1, Qb[n][1], acc_s[m][n], 0, 0, 0);
            }
        }
        #pragma unroll
        for (int m = 0; m < 4; m++)
            #pragma unroll
            for (int n = 0; n < 4; n++) {
                float4 mv = *(const float4*)(mask + (size_t)(wq0 + n * 16 + l15) * 256 + kt * 64 + m * 16 + l4 * 4);
                acc_s[m][n][0] = acc_s[m][n][0] * 0.125f + (mv.x - 0.5f) * 20.f;
                acc_s[m][n][1] = acc_s[m][n][1] * 0.125f + (mv.y - 0.5f) * 20.f;
                acc_s[m][n][2] = acc_s[m][n][2] * 0.125f + (mv.z - 0.5f) * 20.f;
                acc_s[m][n][3] = acc_s[m][n][3] * 0.125f + (mv.w - 0.5f) * 20.f;
            }
        #pragma unroll
        for (int n = 0; n < 4; n++) {
            float tmax = acc_s[0][n][0];
            #pragma unroll
            for (int m = 0; m < 4; m++)
                #pragma unroll
                for (int r = 0; r < 4; r++) tmax = fmaxf(tmax, acc_s[m][n][r]);
            tmax = fmaxf(tmax, __shfl_xor(tmax, 16, 64));
            tmax = fmaxf(tmax, __shfl_xor(tmax, 32, 64));
            float newm = fmaxf(m_run[n], tmax);
            float corr = __expf(m_run[n] - newm);
            m_run[n] = newm;
            float esum = 0.f;
            #pragma unroll
            for (int m = 0; m < 4; m++) {
                #pragma unroll
                for (int r = 0; r < 4; r++) {
                    float p = __expf(acc_s[m][n][r] - newm);
                    acc_s[m][n][r] = p;
                    esum += p;
                }
            }
            esum += __shfl_xor(esum, 16, 64);
            esum += __shfl_xor(esum, 32, 64);
            l_run[n] = l_run[n] * corr + esum;
            #pragma unroll
            for (int m = 0; m < 4; m++) {
                acc_o[m][n][0] *= corr; acc_o[m][n][1] *= corr;
                acc_o[m][n][2] *= corr; acc_o[m][n][3] *= corr;
            }
            #pragma unroll
            for (int m = 0; m < 4; m++) {
                uint2 pw = { pack2(acc_s[m][n][0], acc_s[m][n][1]),
                             pack2(acc_s[m][n][2], acc_s[m][n][3]) };
                *(uint2*)&Pt[wave][n * 16 + l15][m * 16 + l4 * 4] = pw;
            }
        }
        #pragma unroll
        for (int kr = 0; kr < 2; kr++) {
            bf16x8 Va[4], Pb[4];
            #pragma unroll
            for (int m = 0; m < 4; m++)
                Va[m] = *(const bf16x8*)&Vt[m * 16 + l15][kt * 64 + kr * 32 + l4 * 8];
            #pragma unroll
            for (int n = 0; n < 4; n++)
                Pb[n] = *(const bf16x8*)&Pt[wave][n * 16 + l15][kr * 32 + l4 * 8];
            #pragma unroll
            for (int m = 0; m < 4; m++)
                #pragma unroll
                for (int n = 0; n < 4; n++)
                    acc_o[m][n] = __builtin_amdgcn_mfma_f32_16x16x32_bf16(Va[m], Pb[n], acc_o[m][n], 0, 0, 0);
        }
    }

    float inv[4];
    #pragma unroll
    for (int n = 0; n < 4; n++) inv[n] = 1.f / l_run[n];
    #pragma unroll
    for (int m = 0; m < 4; m++)
        #pragma unroll
        for (int n = 0; n < 4; n++) {
            ushort4 ov = { f2bf(acc_o[m][n][0] * inv[n]), f2bf(acc_o[m][n][1] * inv[n]),
                           f2bf(acc_o[m][n][2] * inv[n]), f2bf(acc_o[m][n][3] * inv[n]) };
            *(ushort4*)(O + (rbase + wq0 + n * 16 + l15) * 512 + head * 64 + m * 16 + l4 * 4) = ov;
        }
}

// ---------------------------------------------------------------- temporal attention
__global__ __launch_bounds__(256) void tattn_k(const bfu* __restrict__ QKV,
                                               const float* __restrict__ mask,
                                               bfu* __restrict__ O) {
    __shared__ __align__(16) bfu Ks[16][520];
    __shared__ __align__(16) bfu Vs[16][520];
    __shared__ __align__(16) bfu Qs[16][520];
    const int bp = blockIdx.x, b = bp >> 8, p = bp & 255;
    const int tid = threadIdx.x, wave = tid >> 6, lane = tid & 63;
    const size_t rb = (size_t)bp * 16;
    {
        int r = tid >> 4, off = (tid & 15) * 32;
        const bfu* qp = QKV + (rb + r) * 1536 + off;
        const bfu* kp = qp + 512;
        const bfu* vp = qp + 1024;
        #pragma unroll
        for (int c = 0; c < 32; c += 8) {
            *(uint4*)&Qs[r][off + c] = *(const uint4*)(qp + c);
            *(uint4*)&Ks[r][off + c] = *(const uint4*)(kp + c);
            *(uint4*)&Vs[r][off + c] = *(const uint4*)(vp + c);
        }
    }
    __syncthreads();
    const int qq = lane >> 4, kk = lane & 15;
    const int dp4 = (lane & 15) * 4;
    const int abase = lane & 48;
    for (int hh = 0; hh < 2; hh++) {
        const int head = wave * 2 + hh, hoff = head * 64;
        for (int qp4 = 0; qp4 < 4; qp4++) {
            const int q = qp4 * 4 + qq;
            float dot = 0.f;
            #pragma unroll
            for (int dg = 0; dg < 8; dg++) {
                const unsigned int* kp = (const unsigned int*)&Ks[kk][hoff + dg * 8];
                const unsigned int* qp = (const unsigned int*)&Qs[q][hoff + dg * 8];
                #pragma unroll
                for (int c = 0; c < 4; c++) {
                    unsigned int ku = kp[c], qu = qp[c];
                    dot += u_lo(ku) * u_lo(qu) + u_hi(ku) * u_hi(qu);
                }
            }
            float sc = dot * 0.125f + (mask[q * 16 + kk] - 0.5f) * 20.f;
            float m = sc;
            #pragma unroll
            for (int off = 1; off < 16; off <<= 1) m = fmaxf(m, __shfl_xor(m, off, 64));
            float e = __expf(sc - m);
            float sum = e;
            #pragma unroll
            for (int off = 1; off < 16; off <<= 1) sum += __shfl_xor(sum, off, 64);
            float a = e / sum;
            float o0 = 0.f, o1 = 0.f, o2 = 0.f, o3 = 0.f;
            #pragma unroll
            for (int k = 0; k < 16; k++) {
                float ak = __shfl(a, abase + k, 64);
                const unsigned int* vp = (const unsigned int*)&Vs[k][hoff + dp4];
                unsigned int u0 = vp[0], u1 = vp[1];
                o0 += ak * u_lo(u0); o1 += ak * u_hi(u0);
                o2 += ak * u_lo(u1); o3 += ak * u_hi(u1);
            }
            size_t orow = ((size_t)((b * 16 + q) * 256 + p)) * 512 + hoff + dp4;
            ushort4 ov = { f2bf(o0), f2bf(o1), f2bf(o2), f2bf(o3) };
            *(ushort4*)(O + orow) = ov;
        }
    }
}

// ---------------------------------------------------------------- unpatchify (bf16 -> fp32 out)
__global__ __launch_bounds__(256) void unpatch_k(const bfu* __restrict__ patches,
                                                 float* __restrict__ pred) {
    int idx = blockIdx.x * 256 + threadIdx.x;   // B*IMG*IMG
    int c = idx & 255;
    int r = (idx >> 8) & 255;
    int bb = idx >> 16;
    int gr = r >> 4, pr = r & 15, gc = c >> 4, pc = c & 15;
    pred[idx] = bf2f(patches[((size_t)(bb * 256 + gr * 16 + gc) << 8) + pr * 16 + pc]);
}

// ---------------------------------------------------------------- host side
static inline void run_gseg(int act,
                            const bfu* A0, const bfu* W0, int K0,
                            const bfu* A1, const bfu* W1, int K1,
                            const bfu* A2, const bfu* W2, int K2,
                            const bfu* A3, const bfu* W3, int K3, int nseg,
                            const float* bias, const bfu* addTo, bfu* C,
                            int M, int N, hipStream_t s) {
    int nx = N / 128;
    int nwg = nx * (M / 128);
    if (act == 0)
        gemm3_k<0><<<nwg, 256, 0, s>>>(A0, W0, K0, A1, W1, K1, A2, W2, K2, A3, W3, K3,
                                       nseg, bias, addTo, C, M, N, nx);
    else if (act == 1)
        gemm3_k<1><<<nwg, 256, 0, s>>>(A0, W0, K0, A1, W1, K1, A2, W2, K2, A3, W3, K3,
                                       nseg, bias, addTo, C, M, N, nx);
    else
        gemm3_k<2><<<nwg, 256, 0, s>>>(A0, W0, K0, A1, W1, K1, A2, W2, K2, A3, W3, K3,
                                       nseg, bias, addTo, C, M, N, nx);
}

static inline void run_g(int act, const bfu* A, const bfu* W, int K,
                         const float* bias, const bfu* addTo, bfu* C,
                         int M, int N, hipStream_t s) {
    run_gseg(act, A, W, K, nullptr, nullptr, 0, nullptr, nullptr, 0,
             nullptr, nullptr, 0, 1, bias, addTo, C, M, N, s);
}

extern "C" void kernel_launch(void* const* d_in, const int* in_sizes, int n_in,
                              void* d_out, int out_size, void* d_ws, size_t ws_size,
                              hipStream_t stream) {
    const float* x        = (const float*)d_in[0];
    const float* s_mask   = (const float*)d_in[1];
    const float* t_mask   = (const float*)d_in[2];
    const float* wo_masks = (const float*)d_in[3];
    const float* ff_masks = (const float*)d_in[4];
    const float* skip_masks = (const float*)d_in[5];
    const float* head_mask  = (const float*)d_in[6];
    const float* patch_w  = (const float*)d_in[7];
    const float* patch_b  = (const float*)d_in[8];
    const float* tpos     = (const float*)d_in[9];
    const float* spos     = (const float*)d_in[10];
    const float* sq_w = (const float*)d_in[11];
    const float* sq_b = (const float*)d_in[12];
    const float* sk_w = (const float*)d_in[13];
    const float* sk_b = (const float*)d_in[14];
    const float* sv_w = (const float*)d_in[15];
    const float* sv_b = (const float*)d_in[16];
    const float* tq_w = (const float*)d_in[17];
    const float* tq_b = (const float*)d_in[18];
    const float* tk_w = (const float*)d_in[19];
    const float* tk_b = (const float*)d_in[20];
    const float* tv_w = (const float*)d_in[21];
    const float* tv_b = (const float*)d_in[22];
    const float* so_w = (const float*)d_in[23];
    const float* to_w = (const float*)d_in[24];
    const float* ln_s_g = (const float*)d_in[25];
    const float* ln_s_b = (const float*)d_in[26];
    const float* ln_t_g = (const float*)d_in[27];
    const float* ln_t_b = (const float*)d_in[28];
    const float* ln_f_g = (const float*)d_in[29];
    const float* ln_f_b = (const float*)d_in[30];
    const float* ff1_w = (const float*)d_in[31];
    const float* ff1_b = (const float*)d_in[32];
    const float* ff2_w = (const float*)d_in[33];
    const float* ff2_b = (const float*)d_in[34];
    const float* skip_w = (const float*)d_in[35];
    const float* lnf_g = (const float*)d_in[36];
    const float* lnf_b = (const float*)d_in[37];
    const float* head_w = (const float*)d_in[38];
    const float* head_b = (const float*)d_in[39];

    bfu* ws = (bfu*)d_ws;
    const size_t ACTE = (size_t)NTOK * HH;     // 8,388,608 elems (16 MB bf16)
    bfu* acts[5];
    for (int i = 0; i < 5; i++) acts[i] = ws + i * ACTE;
    bfu* xln = ws + 5 * ACTE;
    bfu* qkv = ws + 6 * ACTE;      // NTOK x 1536 fused (spans 3*ACTE)
    bfu* ob  = ws + 9 * ACTE;
    bfu* f1  = qkv;                // NTOK*FFDIM = 4*ACTE, spans qkv..ob
    bfu* xp      = ob;             // patchified pixels (NTOK*PQ), pre-layer phase
    bfu* lastln  = xln;            // final LN rows (1024)
    bfu* patches = qkv;            // head output (1024*256)
    bfu* wlayer = ws + 10 * ACTE;            // per-layer bf16 weights (WL_TOT)
    bfu* wpers  = wlayer + WL_TOT;           // persistent bf16 weights (WP_TOT)
    float* bias_s = (float*)(wpers + WP_TOT);
    float* bias_t = bias_s + 1536;
    // total ws use: (10*ACTE + WL_TOT + WP_TOT)*2 + 3072*4 bytes ~= 171.5 MB

    // ---- persistent weight conversion (skips, head, patch)
    convpers_k<<<WP_TOT / 8 / 256, 256, 0, stream>>>(skip_w, skip_masks, head_w, head_mask,
                                                     patch_w, wpers);

    // ---- patch embed
    patchify_k<<<NTOK * PQ / 256, 256, 0, stream>>>(x, xp);
    run_g(0, xp, wpers + WP_PATCH, PQ, patch_b, nullptr, acts[0], NTOK, HH, stream);
    addpos_k<<<NTOK * HH / 256, 256, 0, stream>>>(acts[0], tpos, spos);

    const size_t WS = 512 * 512;
    const size_t FS = 2048 * 512;
    const int srcs[6] = {0, 0, 1, 0, 1, 2};
    const int tgts[6] = {2, 3, 3, 4, 4, 4};

    for (int i = 0; i < LLAYERS; i++) {
        bfu* h   = acts[i];
        bfu* hn  = acts[i + 1];
        // ---- convert this layer's weights (bf16, masks fused, QKV concatenated)
        convw_k<<<WL_TOT / 8 / 256, 256, 0, stream>>>(
            sq_w + i * WS, sk_w + i * WS, sv_w + i * WS, so_w + i * WS,
            tq_w + i * WS, tk_w + i * WS, tv_w + i * WS, to_w + i * WS,
            ff1_w + i * FS, ff2_w + i * FS,
            wo_masks + i * WS, ff_masks + i * FS,
            sq_b + i * HH, sk_b + i * HH, sv_b + i * HH,
            tq_b + i * HH, tk_b + i * HH, tv_b + i * HH,
            wlayer, bias_s, bias_t);
        // ---- spatial attention
        ln_k<<<NTOK / 4, 256, 0, stream>>>(h, ln_s_g + i * HH, ln_s_b + i * HH, xln, NTOK, 0);
        run_g(0, xln, wlayer + WL_SQKV, HH, bias_s, nullptr, qkv, NTOK, 1536, stream);
        sattn_k<<<BB * TT * NHEADS, 256, 0, stream>>>(qkv, s_mask, ob);
        run_g(0, ob, wlayer + WL_SO, HH, nullptr, h, hn, NTOK, HH, stream);
        // ---- temporal attention (rows in (b,p,t) order)
        ln_k<<<NTOK / 4, 256, 0, stream>>>(hn, ln_t_g + i * HH, ln_t_b + i * HH, xln, NTOK, 1);
        run_g(0, xln, wlayer + WL_TQKV, HH, bias_t, nullptr, qkv, NTOK, 1536, stream);
        tattn_k<<<BB * PPATCH, 256, 0, stream>>>(qkv, t_mask, ob);   // writes (b,t,p)
        run_g(0, ob, wlayer + WL_TO, HH, nullptr, hn, hn, NTOK, HH, stream);
        // ---- feed forward (+ fused skip connections into layer output)
        ln_k<<<NTOK / 4, 256, 0, stream>>>(hn, ln_f_g + i * HH, ln_f_b + i * HH, xln, NTOK, 0);
        run_g(1, xln, wlayer + WL_FF1, HH, ff1_b + i * FFDIM, nullptr, f1, NTOK, FFDIM, stream);
        {
            const bfu* Aseg[4] = { f1, nullptr, nullptr, nullptr };
            const bfu* Wseg[4] = { wlayer + WL_FF2, nullptr, nullptr, nullptr };
            int Kseg[4] = { FFDIM, 0, 0, 0 };
            int ns = 1;
            for (int si = 0; si < 6; si++) {
                if (tgts[si] != i + 1) continue;
                Aseg[ns] = acts[srcs[si]];
                Wseg[ns] = wpers + WP_SKIP + si * WS;
                Kseg[ns] = HH;
                ns++;
            }
            run_gseg(0, Aseg[0], Wseg[0], Kseg[0], Aseg[1], Wseg[1], Kseg[1],
                     Aseg[2], Wseg[2], Kseg[2], Aseg[3], Wseg[3], Kseg[3], ns,
                     ff2_b + i * HH, hn, hn, NTOK, HH, stream);
        }
    }

    // ---- head
    ln_k<<<(BB * PPATCH) / 4, 256, 0, stream>>>(acts[4], lnf_g, lnf_b, lastln, BB * PPATCH, 2);
    run_g(2, lastln, wpers + WP_HEAD, HH, head_b, nullptr, patches, BB * PPATCH, PQ, stream);
    unpatch_k<<<BB * IMGSZ * IMGSZ / 256, 256, 0, stream>>>(patches, (float*)d_out);
}